// Round 8
// baseline (369.140 us; speedup 1.0000x reference)
//
#include <hip/hip_runtime.h>
#include <math.h>

#define NN 2048

typedef __attribute__((ext_vector_type(8))) short short8;
typedef __attribute__((ext_vector_type(4))) float f32x4;
typedef __attribute__((ext_vector_type(2))) float f32x2;

__device__ inline short f2bf(float x) {
  union { float f; unsigned u; } v; v.f = x;
  unsigned r = v.u + 0x7fff + ((v.u >> 16) & 1);  // RNE
  return (short)(r >> 16);
}
__device__ inline float bf2f(short h) {
  union { unsigned u; float f; } t;
  t.u = ((unsigned)(unsigned short)h) << 16;
  return t.f;
}

// ---------------------------------------------------------------------------
// Layer-1 GIN MLP (FIN=32) + init duties: zero stats workspace + counter,
// split W5 to bf16 hi/lo, self-computed aggregation prefix from nf.
// 64 blocks x 256 threads.
// ---------------------------------------------------------------------------
__global__ __launch_bounds__(256) void k_l1(
    const float* __restrict__ nf, const float* __restrict__ W5,
    const float* __restrict__ epsp,
    const float* __restrict__ Wa, const float* __restrict__ ba,
    const float* __restrict__ Wb, const float* __restrict__ bb,
    float* __restrict__ OUT, float* __restrict__ csum,
    short* __restrict__ w5hi, short* __restrict__ w5lo,
    double* __restrict__ zbase, int* __restrict__ cnt) {
  __shared__ float xh[32 * 33];
  __shared__ float Ts[32 * 65];
  __shared__ float Was[32 * 64];
  __shared__ float Wbs[64 * 64];
  __shared__ float pr[32 * 36];
  __shared__ float spref[32];
  __shared__ float bas[64];
  __shared__ float bbs[64];
  __shared__ float ssum[64];
  int tid = threadIdx.x, blk = blockIdx.x;
  int gtid = blk * 256 + tid;
  int node0 = blk * 32;
  float ep = 1.f + epsp[0];

  // init duties
  if (gtid < 10240) zbase[gtid] = 0.0;  // statsM(2048) + stats5(8192)
  if (gtid == 0) *cnt = 0;
  if (gtid < 2048) {
    int c = gtid >> 5, k = gtid & 31;
    float wv = W5[k * 64 + c];
    short hi = f2bf(wv);
    w5hi[c * 32 + k] = hi;
    w5lo[c * 32 + k] = f2bf(wv - bf2f(hi));
  }

  // stage x tile (32 rows x 8 float4 = 1 per thread)
  {
    int row = tid >> 3, c4 = (tid & 7) * 4;
    float4 v = *(const float4*)(nf + (size_t)(node0 + row) * 32 + c4);
    float* dst = xh + row * 33 + c4;
    dst[0] = v.x; dst[1] = v.y; dst[2] = v.z; dst[3] = v.w;
  }
  // self prefix: sum of all nf rows < node0 (independent pipelined loads)
  {
    int q = tid & 7, s = tid >> 3;
    float a0 = 0.f, a1 = 0.f, a2 = 0.f, a3 = 0.f;
    for (int flat = tid; flat < blk * 256; flat += 256) {
      const float4 v = *(const float4*)(nf + (size_t)(flat >> 3) * 32 + q * 4);
      a0 += v.x; a1 += v.y; a2 += v.z; a3 += v.w;
    }
    float* d = pr + s * 36 + q * 4;
    d[0] = a0; d[1] = a1; d[2] = a2; d[3] = a3;
  }
  for (int idx = tid; idx < 32 * 16; idx += 256)
    *(float4*)(Was + idx * 4) = *(const float4*)(Wa + idx * 4);
  for (int idx = tid; idx < 64 * 16; idx += 256)
    *(float4*)(Wbs + idx * 4) = *(const float4*)(Wb + idx * 4);
  if (tid < 64) { bas[tid] = ba[tid]; bbs[tid] = bb[tid]; ssum[tid] = 0.f; }
  __syncthreads();
  if (tid < 32) {
    float s = 0.f;
    for (int r = 0; r < 32; r++) s += pr[r * 36 + tid];
    spref[tid] = s;
  }
  __syncthreads();
  // in-chunk exclusive scan (FIN=32)
  {
    int w = tid >> 6, lane = tid & 63, half = lane >> 5, nl = lane & 31;
#pragma unroll
    for (int p = 0; p < 4; p++) {
      int f = w * 8 + 2 * p + half;
      float v = xh[nl * 33 + f];
      float s = v;
#pragma unroll
      for (int d = 1; d < 32; d <<= 1) {
        float t = __shfl_up(s, (unsigned)d, 32);
        if (nl >= d) s += t;
      }
      xh[nl * 33 + f] = fmaf(ep, v, spref[f] + (s - v));
    }
  }
  __syncthreads();
  // Phase A: T = relu(xh @ Wa + ba)
  {
    int n = tid >> 3, c0 = (tid & 7) * 8;
    float acc[8];
#pragma unroll
    for (int k = 0; k < 8; k++) acc[k] = bas[c0 + k];
    for (int f = 0; f < 32; f++) {
      float xv = xh[n * 33 + f];
#pragma unroll
      for (int k = 0; k < 8; k++) acc[k] = fmaf(xv, Was[f * 64 + c0 + k], acc[k]);
    }
#pragma unroll
    for (int k = 0; k < 8; k++) Ts[n * 65 + c0 + k] = fmaxf(acc[k], 0.f);
  }
  __syncthreads();
  // Phase B: OUT = relu(T @ Wb + bb), chunk-sum out
  {
    int n = tid >> 3, c0 = (tid & 7) * 8;
    float acc[8];
#pragma unroll
    for (int k = 0; k < 8; k++) acc[k] = bbs[c0 + k];
    for (int f = 0; f < 64; f++) {
      float tv = Ts[n * 65 + f];
#pragma unroll
      for (int k = 0; k < 8; k++) acc[k] = fmaf(tv, Wbs[f * 64 + c0 + k], acc[k]);
    }
#pragma unroll
    for (int k = 0; k < 8; k++) {
      float r = fmaxf(acc[k], 0.f);
      atomicAdd(&ssum[c0 + k], r);
      OUT[(size_t)(node0 + n) * 64 + c0 + k] = r;
    }
  }
  __syncthreads();
  if (tid < 64) csum[blk * 64 + tid] = ssum[tid];
}

// ---------------------------------------------------------------------------
// GIN MLP kernel for a 32-node chunk, FIN=64 (layers 2/3), CS-prefix based.
// ---------------------------------------------------------------------------
template <int FIN, int FOUT, bool STATS, bool ADDX, bool AFFINE, bool CSUM>
__global__ __launch_bounds__(256) void k_mlp32(
    const float* __restrict__ X, const float* __restrict__ CS,
    const float* __restrict__ epsp,
    const float* __restrict__ Wa, const float* __restrict__ ba,
    const float* __restrict__ Wb, const float* __restrict__ bb,
    float* __restrict__ OUT, const float* __restrict__ XINIT,
    double* __restrict__ statsW, const double* __restrict__ statsRd,
    const float* __restrict__ bng, const float* __restrict__ bnb,
    float* __restrict__ csum) {
  __shared__ float xh[32 * (FIN + 1)];
  __shared__ float Ts[32 * 65];
  __shared__ float Was[FIN * 64];
  __shared__ float Wbs[64 * FOUT];
  __shared__ float spref[FIN];
  __shared__ float part[4 * FIN];
  __shared__ float bas[64];
  __shared__ float bbs[FOUT];
  __shared__ float ssum[64];
  __shared__ float ssq[64];
  __shared__ float affa[64];
  __shared__ float affb[64];
  int tid = threadIdx.x;
  int blk = blockIdx.x;
  int node0 = blk * 32;
  float ep = 1.f + epsp[0];

  if (AFFINE) {
    if (tid < 64) {
      double s1 = 0.0, s2 = 0.0;
#pragma unroll
      for (int r = 0; r < 16; r++) {
        s1 += statsRd[r * 128 + tid];
        s2 += statsRd[r * 128 + 64 + tid];
      }
      double mean = s1 * (1.0 / 2048.0);
      double var = s2 * (1.0 / 2048.0) - mean * mean;
      if (var < 0.0) var = 0.0;
      float a = (float)((double)bng[tid] / sqrt(var + 1e-5));
      affa[tid] = a;
      affb[tid] = fmaf(-(float)mean, a, bnb[tid]);
    }
    __syncthreads();
  }

  for (int idx = tid; idx < 32 * FIN / 4; idx += 256) {
    int row = idx / (FIN / 4), c4 = (idx % (FIN / 4)) * 4;
    float4 v = *(const float4*)(X + (size_t)(node0 + row) * FIN + c4);
    if (AFFINE) {
      v.x = fmaf(affa[c4 + 0], v.x, affb[c4 + 0]);
      v.y = fmaf(affa[c4 + 1], v.y, affb[c4 + 1]);
      v.z = fmaf(affa[c4 + 2], v.z, affb[c4 + 2]);
      v.w = fmaf(affa[c4 + 3], v.w, affb[c4 + 3]);
    }
    float* dst = xh + row * (FIN + 1) + c4;
    dst[0] = v.x; dst[1] = v.y; dst[2] = v.z; dst[3] = v.w;
  }
  if (tid < 4 * FIN) {
    int g = tid / FIN, f = tid % FIN;
    float s = 0.f;
    for (int c = g; c < blk; c += 4) s += CS[c * FIN + f];
    part[tid] = s;
  }
  for (int idx = tid; idx < FIN * 16; idx += 256)
    *(float4*)(Was + idx * 4) = *(const float4*)(Wa + idx * 4);
  for (int idx = tid; idx < FOUT * 16; idx += 256)
    *(float4*)(Wbs + idx * 4) = *(const float4*)(Wb + idx * 4);
  if (tid < 64) bas[tid] = ba[tid];
  if (tid < FOUT) bbs[tid] = bb[tid];
  if ((STATS || CSUM) && tid < 64) { ssum[tid] = 0.f; ssq[tid] = 0.f; }
  __syncthreads();

  if (tid < FIN) {
    float s = part[tid] + part[FIN + tid] + part[2 * FIN + tid] + part[3 * FIN + tid];
    if (AFFINE) s = fmaf(affa[tid], s, (float)(32 * blk) * affb[tid]);
    spref[tid] = s;
  }
  __syncthreads();

  {
    int w = tid >> 6, lane = tid & 63, half = lane >> 5, nl = lane & 31;
#pragma unroll
    for (int p = 0; p < FIN / 8; p++) {
      int f = w * (FIN / 4) + 2 * p + half;
      float v = xh[nl * (FIN + 1) + f];
      float s = v;
#pragma unroll
      for (int d = 1; d < 32; d <<= 1) {
        float t = __shfl_up(s, (unsigned)d, 32);
        if (nl >= d) s += t;
      }
      xh[nl * (FIN + 1) + f] = fmaf(ep, v, spref[f] + (s - v));
    }
  }
  __syncthreads();

  {
    int n = tid >> 3, c0 = (tid & 7) * 8;
    float acc[8];
#pragma unroll
    for (int k = 0; k < 8; k++) acc[k] = bas[c0 + k];
    for (int f = 0; f < FIN; f++) {
      float xv = xh[n * (FIN + 1) + f];
#pragma unroll
      for (int k = 0; k < 8; k++) acc[k] = fmaf(xv, Was[f * 64 + c0 + k], acc[k]);
    }
#pragma unroll
    for (int k = 0; k < 8; k++) Ts[n * 65 + c0 + k] = fmaxf(acc[k], 0.f);
  }
  __syncthreads();

  {
    constexpr int CC = FOUT / 8;
    int n = tid >> 3, c0 = (tid & 7) * CC;
    float acc[CC];
#pragma unroll
    for (int k = 0; k < CC; k++) acc[k] = bbs[c0 + k];
    for (int f = 0; f < 64; f++) {
      float tv = Ts[n * 65 + f];
#pragma unroll
      for (int k = 0; k < CC; k++) acc[k] = fmaf(tv, Wbs[f * FOUT + c0 + k], acc[k]);
    }
#pragma unroll
    for (int k = 0; k < CC; k++) {
      float r = fmaxf(acc[k], 0.f);
      if (STATS || CSUM) atomicAdd(&ssum[c0 + k], r);
      if (STATS) atomicAdd(&ssq[c0 + k], r * r);
      if (ADDX) r += XINIT[(size_t)(node0 + n) * FOUT + c0 + k];
      OUT[(size_t)(node0 + n) * FOUT + c0 + k] = r;
    }
  }
  if (STATS || CSUM) {
    __syncthreads();
    if (tid < FOUT) {
      if (CSUM) csum[blk * FOUT + tid] = ssum[tid];
      if (STATS) {
        int rep = blk & 15;
        atomicAdd(&statsW[rep * 128 + tid], (double)ssum[tid]);
        atomicAdd(&statsW[rep * 128 + 64 + tid], (double)ssq[tid]);
      }
    }
  }
}

// ---------------------------------------------------------------------------
// Tile decode: t -> (bi,bj), bi<=bj, row-major over upper triangle of 128x128.
// ---------------------------------------------------------------------------
__device__ inline void tile_decode(int t, int& bi, int& bj) {
  bi = (int)((257.0f - sqrtf(66049.0f - 8.0f * (float)t)) * 0.5f);
  if (bi > 127) bi = 127;
  while (bi > 0 && bi * (257 - bi) / 2 > t) bi--;
  while ((bi + 1) * (256 - bi) / 2 <= t) bi++;
  bj = bi + (t - bi * (257 - bi) / 2);
}

// Truncation-split of 8 fp32 products into hi/lo bf16 fragments (edge2).
__device__ inline void split_pack(const float m[8], short8& ah, short8& al) {
  unsigned uh[8], ul[8];
#pragma unroll
  for (int e = 0; e < 8; e++) {
    union { float f; unsigned u; } um; um.f = m[e];
    uh[e] = um.u;
    union { unsigned u; float f; } hf; hf.u = um.u & 0xffff0000u;
    union { float f; unsigned u; } lf; lf.f = m[e] - hf.f;
    ul[e] = lf.u;
  }
  union { unsigned i[4]; short8 s; } ph, pl;
#pragma unroll
  for (int k = 0; k < 4; k++) {
    ph.i[k] = __builtin_amdgcn_perm(uh[2 * k + 1], uh[2 * k], 0x07060302u);
    pl.i[k] = __builtin_amdgcn_perm(ul[2 * k + 1], ul[2 * k], 0x07060302u);
  }
  ah = ph.s;
  al = pl.s;
}

// ---------------------------------------------------------------------------
// Edge pass 1: per-channel sum / sumsq of e = leaky(m@W5 + b5).
// 2-term MFMA (m hi-only x exact W5), packed-fp32 epilogue, last-block fold
// of stats -> prep (delta-logit weights for edge2).
// ---------------------------------------------------------------------------
__global__ __launch_bounds__(256) void k_edge1m(
    const float* __restrict__ H3, const short* __restrict__ W5Th,
    const short* __restrict__ W5Tl, const float* __restrict__ b5,
    double* __restrict__ stats5, int T, int stride, int* __restrict__ cnt,
    const float* __restrict__ bn5g, const float* __restrict__ bn5b,
    const float* __restrict__ W6, const float* __restrict__ b6,
    float* __restrict__ prep, double ecnt) {
  __shared__ float sI[16][36];
  __shared__ float sJ[16][36];
  __shared__ float ssum[64], ssq[64];
  __shared__ int amlast;
  __shared__ double foldd[128];
  __shared__ float sdel[64];
  int tid = threadIdx.x;
  int w = tid >> 6, lane = tid & 63;
  int quad = lane >> 4, l15 = lane & 15;
  int q8 = quad * 8;
  if (tid < 64) { ssum[tid] = 0.f; ssq[tid] = 0.f; }

  short8 bh[4], bl[4];
  float b5v[4];
#pragma unroll
  for (int nt = 0; nt < 4; nt++) {
    bh[nt] = *(const short8*)(W5Th + (nt * 16 + l15) * 32 + q8);
    bl[nt] = *(const short8*)(W5Tl + (nt * 16 + l15) * 32 + q8);
    b5v[nt] = b5[nt * 16 + l15];
  }
  f32x2 aS[4], aQ[4];
#pragma unroll
  for (int nt = 0; nt < 4; nt++) {
    aS[nt] = (f32x2){0.f, 0.f};
    aQ[nt] = (f32x2){0.f, 0.f};
  }

  for (int t = blockIdx.x; t < T; t += stride) {
    int bi, bj;
    tile_decode(t, bi, bj);
    __syncthreads();
    {
      int row = tid >> 3, c4 = (tid & 7) * 4;
      int grow = (row < 16) ? (bi * 16 + row) : (bj * 16 + row - 16);
      float4 v = *(const float4*)(H3 + (size_t)grow * 32 + c4);
      float* dst = (row < 16) ? &sI[row][c4] : &sJ[row - 16][c4];
      *(float4*)dst = v;
    }
    __syncthreads();
    const float* pJ = &sJ[l15][q8];
    float4 j0 = *(const float4*)pJ, j1 = *(const float4*)(pJ + 4);
    short8 ah[4];
#pragma unroll
    for (int mt = 0; mt < 4; mt++) {
      const float* pI = &sI[4 * w + mt][q8];
      float4 i0 = *(const float4*)pI, i1 = *(const float4*)(pI + 4);
      union { float f[8]; unsigned u[8]; } p;
      p.f[0] = i0.x * j0.x; p.f[1] = i0.y * j0.y;
      p.f[2] = i0.z * j0.z; p.f[3] = i0.w * j0.w;
      p.f[4] = i1.x * j1.x; p.f[5] = i1.y * j1.y;
      p.f[6] = i1.z * j1.z; p.f[7] = i1.w * j1.w;
      union { unsigned i[4]; short8 s; } pk;
#pragma unroll
      for (int k = 0; k < 4; k++)
        pk.i[k] = __builtin_amdgcn_perm(p.u[2 * k + 1], p.u[2 * k], 0x07060302u);
      ah[mt] = pk.s;
    }
    bool diag = (bi == bj);
#pragma unroll
    for (int mt = 0; mt < 4; mt++) {
      int iRow = bi * 16 + 4 * w + mt;
#pragma unroll
      for (int nt = 0; nt < 4; nt++) {
        float bb = b5v[nt];
        f32x4 z = (f32x4){bb, bb, bb, bb};
        z = __builtin_amdgcn_mfma_f32_16x16x32_bf16(ah[mt], bl[nt], z, 0, 0, 0);
        z = __builtin_amdgcn_mfma_f32_16x16x32_bf16(ah[mt], bh[nt], z, 0, 0, 0);
        if (diag) {
          float er[4];
#pragma unroll
          for (int r = 0; r < 4; r++) {
            float e = fmaxf(z[r], z[r] * 0.01f);
            int jCol = bj * 16 + quad * 4 + r;
            er[r] = (iRow < jCol) ? e : 0.f;
          }
          aS[nt] += (f32x2){er[0] + er[2], er[1] + er[3]};
          aQ[nt] += (f32x2){er[0] * er[0] + er[2] * er[2],
                            er[1] * er[1] + er[3] * er[3]};
        } else {
          f32x2 za = (f32x2){z[0], z[1]}, zb = (f32x2){z[2], z[3]};
          f32x2 ea = __builtin_elementwise_max(za, za * 0.01f);
          f32x2 eb = __builtin_elementwise_max(zb, zb * 0.01f);
          aS[nt] += ea + eb;
          aQ[nt] += ea * ea;
          aQ[nt] += eb * eb;
        }
      }
    }
  }
  float accS[4], accQ[4];
#pragma unroll
  for (int nt = 0; nt < 4; nt++) {
    accS[nt] = aS[nt][0] + aS[nt][1];
    accQ[nt] = aQ[nt][0] + aQ[nt][1];
    accS[nt] += __shfl_xor(accS[nt], 16); accS[nt] += __shfl_xor(accS[nt], 32);
    accQ[nt] += __shfl_xor(accQ[nt], 16); accQ[nt] += __shfl_xor(accQ[nt], 32);
  }
  if (quad == 0) {
#pragma unroll
    for (int nt = 0; nt < 4; nt++) {
      atomicAdd(&ssum[nt * 16 + l15], accS[nt]);
      atomicAdd(&ssq[nt * 16 + l15], accQ[nt]);
    }
  }
  __syncthreads();
  if (tid < 64) {
    int rep = blockIdx.x & 63;
    atomicAdd(&stats5[rep * 128 + tid], (double)ssum[tid]);
    atomicAdd(&stats5[rep * 128 + 64 + tid], (double)ssq[tid]);
  }
  // last-finishing block folds stats -> prep (delta-logit weights + base)
  __threadfence();
  if (tid == 0) amlast = (atomicAdd(cnt, 1) == (int)gridDim.x - 1) ? 1 : 0;
  __syncthreads();
  if (amlast) {
    __threadfence();
    if (tid < 128) {
      int c = tid & 63, kind = tid >> 6;
      const volatile double* sp = stats5 + kind * 64 + c;
      double s = 0.0;
      for (int r = 0; r < 64; r++) s += sp[r * 128];
      foldd[tid] = s;
    }
    __syncthreads();
    if (tid < 64) {
      double mean = foldd[tid] / ecnt;
      double var = foldd[64 + tid] / ecnt - mean * mean;
      if (var < 0.0) var = 0.0;
      float a = (float)((double)bn5g[tid] / sqrt(var + 1e-5));
      float sh = (float)((double)bn5b[tid] - mean * (double)a);
      float dwc = W6[2 * tid + 1] - W6[2 * tid];
      prep[tid] = a * dwc;
      sdel[tid] = sh * dwc;
    }
    __syncthreads();
    if (tid == 0) {
      float t = b6[1] - b6[0];
      for (int k = 0; k < 64; k++) t += sdel[k];
      prep[64] = t;
    }
  }
}

// ---------------------------------------------------------------------------
// Edge pass 2 (swapped operands, 3-term split, packed-fp32 epilogue).
// One 16x16 pair tile per block (8256 blocks).
// ---------------------------------------------------------------------------
__global__ __launch_bounds__(256) void k_edge2m(
    const float* __restrict__ H3, const short* __restrict__ W5Th,
    const short* __restrict__ W5Tl, const float* __restrict__ b5,
    const float* __restrict__ prep, float* __restrict__ outp) {
  __shared__ float sI[16][36];
  __shared__ float sJ[16][36];
  int tid = threadIdx.x;
  int w = tid >> 6, lane = tid & 63;
  int quad = lane >> 4, l15 = lane & 15;
  int q8 = quad * 8;
  int bi, bj;
  tile_decode(blockIdx.x, bi, bj);
  {
    int row = tid >> 3, c4 = (tid & 7) * 4;
    int grow = (row < 16) ? (bi * 16 + row) : (bj * 16 + row - 16);
    float4 v = *(const float4*)(H3 + (size_t)grow * 32 + c4);
    float* dst = (row < 16) ? &sI[row][c4] : &sJ[row - 16][c4];
    *(float4*)dst = v;
  }
  short8 ah[4], al[4];
  f32x4 b5v[4], uv[4];
#pragma unroll
  for (int Mt = 0; Mt < 4; Mt++) {
    ah[Mt] = *(const short8*)(W5Th + (Mt * 16 + l15) * 32 + q8);
    al[Mt] = *(const short8*)(W5Tl + (Mt * 16 + l15) * 32 + q8);
    b5v[Mt] = *(const f32x4*)(b5 + Mt * 16 + quad * 4);
    uv[Mt] = *(const f32x4*)(prep + Mt * 16 + quad * 4);
  }
  float dbase = prep[64];
  __syncthreads();

  const float* pJ = &sJ[l15][q8];
  float4 j0 = *(const float4*)pJ, j1 = *(const float4*)(pJ + 4);
  float dkeep = 0.f;
#pragma unroll
  for (int nt = 0; nt < 4; nt++) {
    const float* pI = &sI[4 * w + nt][q8];
    float4 i0 = *(const float4*)pI, i1 = *(const float4*)(pI + 4);
    float m[8] = {i0.x * j0.x, i0.y * j0.y, i0.z * j0.z, i0.w * j0.w,
                  i1.x * j1.x, i1.y * j1.y, i1.z * j1.z, i1.w * j1.w};
    short8 bh, bl;
    split_pack(m, bh, bl);
    f32x2 d2 = (f32x2){0.f, 0.f};
#pragma unroll
    for (int Mt = 0; Mt < 4; Mt++) {
      f32x4 z = b5v[Mt];
      z = __builtin_amdgcn_mfma_f32_16x16x32_bf16(al[Mt], bh, z, 0, 0, 0);
      z = __builtin_amdgcn_mfma_f32_16x16x32_bf16(ah[Mt], bl, z, 0, 0, 0);
      z = __builtin_amdgcn_mfma_f32_16x16x32_bf16(ah[Mt], bh, z, 0, 0, 0);
      f32x2 za = (f32x2){z[0], z[1]}, zb = (f32x2){z[2], z[3]};
      f32x2 ea = __builtin_elementwise_max(za, za * 0.01f);
      f32x2 eb = __builtin_elementwise_max(zb, zb * 0.01f);
      f32x2 ua = (f32x2){uv[Mt][0], uv[Mt][1]};
      f32x2 ub = (f32x2){uv[Mt][2], uv[Mt][3]};
      d2 += ea * ua;
      d2 += eb * ub;
    }
    float d = d2[0] + d2[1];
    d += __shfl_xor(d, 16);
    d += __shfl_xor(d, 32);
    if (quad == nt) dkeep = d;
  }
  int i = bi * 16 + 4 * w + quad;
  int j = bj * 16 + l15;
  if (i < j) {
    float dd = dkeep + dbase;
    float ex = __expf(dd);
    float p0 = 1.f / (1.f + ex);
    float2 p = make_float2(p0, ex * p0);
    *(float2*)(outp + ((size_t)i * NN + j) * 2) = p;
    *(float2*)(outp + ((size_t)j * NN + i) * 2) = p;
  } else if (i == j) {
    *(float2*)(outp + ((size_t)i * NN + i) * 2) = make_float2(0.f, 0.f);
  }
}

// ---------------------------------------------------------------------------
extern "C" void kernel_launch(void* const* d_in, const int* in_sizes, int n_in,
                              void* d_out, int out_size, void* d_ws, size_t ws_size,
                              hipStream_t stream) {
  const float* nf   = (const float*)d_in[1];
  const float* eps1 = (const float*)d_in[2];
  const float* W1a  = (const float*)d_in[3];
  const float* b1a  = (const float*)d_in[4];
  const float* W1b  = (const float*)d_in[5];
  const float* b1b  = (const float*)d_in[6];
  const float* epsm = (const float*)d_in[7];
  const float* Wma  = (const float*)d_in[8];
  const float* bma  = (const float*)d_in[9];
  const float* Wmb  = (const float*)d_in[10];
  const float* bmb  = (const float*)d_in[11];
  const float* bnmg = (const float*)d_in[12];
  const float* bnmb = (const float*)d_in[13];
  const float* epsl = (const float*)d_in[14];
  const float* Wla  = (const float*)d_in[15];
  const float* bla  = (const float*)d_in[16];
  const float* Wlb  = (const float*)d_in[17];
  const float* blb  = (const float*)d_in[18];
  const float* W5   = (const float*)d_in[19];
  const float* b5   = (const float*)d_in[20];
  const float* bn5g = (const float*)d_in[21];
  const float* bn5b = (const float*)d_in[22];
  const float* W6   = (const float*)d_in[23];
  const float* b6   = (const float*)d_in[24];
  double ecnt = (double)in_sizes[25];
  float* out = (float*)d_out;

  float* w = (float*)d_ws;
  float* h1   = w;                         // 2048*64
  float* h2   = w + 131072;                // 2048*64
  float* h3   = w + 262144;                // 2048*32
  float* cs2  = w + 327680;                // 64*64
  float* csr  = w + 331776;                // 64*64
  float* prep = w + 335872;                // 65 (pad)
  int*   cnt  = (int*)(w + 336000);
  short* w5hi = (short*)(w + 336064);      // 2048 shorts
  short* w5lo = (short*)(w + 337088);      // 2048 shorts
  double* statsM = (double*)(w + 338112);  // 2048 doubles (16-rep node stats)
  double* stats5 = statsM + 2048;          // 64*128 doubles

  // node pipeline: 3 kernels (layer 1 absorbs init duties)
  k_l1<<<64, 256, 0, stream>>>(nf, W5, eps1, W1a, b1a, W1b, b1b, h1, cs2,
                               w5hi, w5lo, statsM, cnt);
  k_mlp32<64, 64, true, false, false, true><<<64, 256, 0, stream>>>(
      h1, cs2, epsm, Wma, bma, Wmb, bmb, h2, nullptr, statsM, nullptr,
      nullptr, nullptr, csr);
  k_mlp32<64, 32, false, true, true, false><<<64, 256, 0, stream>>>(
      h2, csr, epsl, Wla, bla, Wlb, blb, h3, nf, nullptr, statsM,
      bnmg, bnmb, nullptr);

  // edge predictor: 2 kernels (edge1's last block folds stats -> prep)
  const int T = 8256;   // 128*129/2 16x16 tiles
  const int NB = 2064;  // edge1: 4 tiles per block (grid-strided)
  k_edge1m<<<NB, 256, 0, stream>>>(h3, w5hi, w5lo, b5, stats5, T, NB, cnt,
                                   bn5g, bn5b, W6, b6, prep, ecnt);
  k_edge2m<<<T, 256, 0, stream>>>(h3, w5hi, w5lo, b5, prep, out);
}